// Round 2
// baseline (97.279 us; speedup 1.0000x reference)
//
#include <hip/hip_runtime.h>

// Chimera: y = (I-A)^{-1} x + D*x where A is the 14x14 grid-DAG adjacency.
// (I-A)^{-1} x computed exactly via forward substitution (A is nilpotent,
// A^27 = 0, so the reference's Neumann product Π(I+A^{2^k}) = Σ A^k = (I-A)^{-1}):
//   z[r,c] = x[r,c] + aL[r,c]*z[r,c-1] + aT[r,c]*z[r-1,c]
// aL = 0.95 * sigmoid(-(dt0+bias)) * rs, aT = 0.95 * sigmoid(-(dt1+bias)) * rs
// rs = 1/sqrt(2) interior, 1 on top row / left col (nie normalization, axis=-2).

#define H_IMG 14
#define W_IMG 14
#define L_NODES 196
#define B_SZ 32
#define NH 24
#define P_DIM 64

__global__ __launch_bounds__(64) void chimera_scan_kernel(
    const float* __restrict__ dt,       // [2, B, NH, 14, 14]
    const float* __restrict__ dt_bias,  // [NH]
    const float* __restrict__ x,        // [B, NH, 196, 64]
    const float* __restrict__ Dvec,     // [NH]
    float* __restrict__ out)            // [B, NH, 196, 64]
{
    const int bh   = blockIdx.x;        // b*NH + h
    const int h    = bh % NH;
    const int lane = threadIdx.x;       // channel p

    const float bias = dt_bias[h];
    const float Dh   = Dvec[h];

    __shared__ float s_aL[L_NODES];
    __shared__ float s_aT[L_NODES];

    const float* dt0 = dt + (size_t)bh * L_NODES;
    const float* dt1 = dt0 + (size_t)B_SZ * NH * L_NODES;

    for (int i = lane; i < L_NODES; i += 64) {
        int r = i / W_IMG;
        int c = i - r * W_IMG;
        // row-normalization: nie=2 interior -> 1/sqrt(2); boundary/corner -> 1
        float rs = (r > 0 && c > 0) ? 0.70710678118654752f : 1.0f;
        float coef = 0.95f * rs;
        // exp(-softplus(v)) == 1/(1+exp(v))
        float e0 = expf(dt0[i] + bias);
        float e1 = expf(dt1[i] + bias);
        s_aL[i] = (c > 0) ? coef / (1.0f + e0) : 0.0f;
        s_aT[i] = (r > 0) ? coef / (1.0f + e1) : 0.0f;
    }
    __syncthreads();

    const float* xb = x   + (size_t)bh * L_NODES * P_DIM + lane;
    float*       yb = out + (size_t)bh * L_NODES * P_DIM + lane;

    // Load the whole (b,h) slab into registers (static indices after unroll);
    // maximizes memory-level parallelism (50 KB of loads in flight per wave).
    float xv[L_NODES];
    #pragma unroll
    for (int i = 0; i < L_NODES; ++i) {
        xv[i] = xb[(size_t)i * P_DIM];
    }

    float zrow[W_IMG];
    #pragma unroll
    for (int c = 0; c < W_IMG; ++c) zrow[c] = 0.0f;

    #pragma unroll
    for (int r = 0; r < H_IMG; ++r) {
        float zl = 0.0f;
        #pragma unroll
        for (int c = 0; c < W_IMG; ++c) {
            const int i = r * W_IMG + c;
            float z = fmaf(s_aL[i], zl, fmaf(s_aT[i], zrow[c], xv[i]));
            zrow[c] = z;
            zl = z;
            yb[(size_t)i * P_DIM] = fmaf(Dh, xv[i], z);
        }
    }
}

extern "C" void kernel_launch(void* const* d_in, const int* in_sizes, int n_in,
                              void* d_out, int out_size, void* d_ws, size_t ws_size,
                              hipStream_t stream) {
    const float* dt      = (const float*)d_in[0];
    const float* dt_bias = (const float*)d_in[1];
    const float* x       = (const float*)d_in[2];
    const float* Dvec    = (const float*)d_in[3];
    float* out = (float*)d_out;

    dim3 grid(B_SZ * NH);
    dim3 block(64);
    chimera_scan_kernel<<<grid, block, 0, stream>>>(dt, dt_bias, x, Dvec, out);
}

// Round 3
// 94.130 us; speedup vs baseline: 1.0334x; 1.0334x over previous
//
#include <hip/hip_runtime.h>

// Chimera: y = (I-A)^{-1} x + D*x, A = nilpotent 14x14 raster-DAG adjacency.
// Exact forward substitution: z[r,c] = x + aL*z[r,c-1] + aT*z[r-1,c].
// v3: x slab staged to LDS with float4 loads; scan reads LDS, stores y direct
// (no global loads pending during scan -> stores never trigger vmcnt waits).

#define H_IMG 14
#define W_IMG 14
#define L_NODES 196
#define B_SZ 32
#define NH 24
#define P_DIM 64
#define SLAB (L_NODES * P_DIM)   // 12544 floats = 49 KiB
#define NCHUNK (SLAB / 256)      // 49 wave-wide 1KB chunks

__global__ __launch_bounds__(64) void chimera_scan_kernel(
    const float* __restrict__ dt,       // [2, B, NH, 14, 14]
    const float* __restrict__ dt_bias,  // [NH]
    const float* __restrict__ x,        // [B, NH, 196, 64]
    const float* __restrict__ Dvec,     // [NH]
    float* __restrict__ out)            // [B, NH, 196, 64]
{
    const int bh   = blockIdx.x;        // b*NH + h
    const int h    = bh % NH;
    const int lane = threadIdx.x;       // channel p

    __shared__ float s_x[SLAB];         // 49 KiB: x slab (per-block bh)
    __shared__ float s_aL[L_NODES];
    __shared__ float s_aT[L_NODES];

    const float bias = dt_bias[h];
    const float Dh   = Dvec[h];

    // --- dt loads first: aL/aT compute overlaps the x staging ---
    const float* dt0 = dt + (size_t)bh * L_NODES;
    const float* dt1 = dt0 + (size_t)(B_SZ * NH) * L_NODES;
    float d0v[4], d1v[4];
    #pragma unroll
    for (int k = 0; k < 4; ++k) {
        int i = lane + 64 * k;
        bool ok = (i < L_NODES);
        d0v[k] = ok ? dt0[ok ? i : 0] : 0.0f;
        d1v[k] = ok ? dt1[ok ? i : 0] : 0.0f;
    }

    // --- stage x slab into LDS, 16 B/lane wide loads ---
    const float* xb = x + (size_t)bh * SLAB;
    #pragma unroll
    for (int k = 0; k < NCHUNK; ++k) {
        float4 v = *reinterpret_cast<const float4*>(xb + (k * 256 + lane * 4));
        *reinterpret_cast<float4*>(s_x + (k * 256 + lane * 4)) = v;
    }

    // --- coefficients: aL = 0.95*sigmoid(-(dt0+bias))*rs, rs = nie^(-1/2) ---
    #pragma unroll
    for (int k = 0; k < 4; ++k) {
        int i = lane + 64 * k;
        if (i < L_NODES) {
            int r = i / W_IMG;
            int c = i - r * W_IMG;
            float rs = (r > 0 && c > 0) ? 0.70710678118654752f : 1.0f;
            float coef = 0.95f * rs;
            // exp(-softplus(v)) == 1/(1+exp(v))
            s_aL[i] = (c > 0) ? coef / (1.0f + expf(d0v[k] + bias)) : 0.0f;
            s_aT[i] = (r > 0) ? coef / (1.0f + expf(d1v[k] + bias)) : 0.0f;
        }
    }

    __syncthreads();

    // --- raster scan; y stored straight to global (fire-and-forget) ---
    float* yb = out + (size_t)bh * SLAB + lane;
    float zrow[W_IMG];
    #pragma unroll
    for (int c = 0; c < W_IMG; ++c) zrow[c] = 0.0f;

    #pragma unroll
    for (int r = 0; r < H_IMG; ++r) {
        float zl = 0.0f;
        #pragma unroll
        for (int c = 0; c < W_IMG; ++c) {
            const int i = r * W_IMG + c;
            float xi = s_x[i * P_DIM + lane];   // 2-way bank access: free
            float z  = fmaf(s_aL[i], zl, fmaf(s_aT[i], zrow[c], xi));
            zrow[c] = z;
            zl = z;
            yb[i * P_DIM] = fmaf(Dh, xi, z);
        }
    }
}

extern "C" void kernel_launch(void* const* d_in, const int* in_sizes, int n_in,
                              void* d_out, int out_size, void* d_ws, size_t ws_size,
                              hipStream_t stream) {
    const float* dt      = (const float*)d_in[0];
    const float* dt_bias = (const float*)d_in[1];
    const float* x       = (const float*)d_in[2];
    const float* Dvec    = (const float*)d_in[3];
    float* out = (float*)d_out;

    dim3 grid(B_SZ * NH);
    dim3 block(64);
    chimera_scan_kernel<<<grid, block, 0, stream>>>(dt, dt_bias, x, Dvec, out);
}

// Round 4
// 94.055 us; speedup vs baseline: 1.0343x; 1.0008x over previous
//
#include <hip/hip_runtime.h>

// Chimera: y = (I-A)^{-1} x + D*x, A = nilpotent 14x14 raster-DAG adjacency.
// Exact forward substitution: z[r,c] = x + aL*z[r,c-1] + aT*z[r-1,c].
// v4: staging via __builtin_amdgcn_global_load_lds width=16 (HBM->LDS direct,
// no VGPR round-trip, single vmcnt(0) drain). dt loads issued first so the
// coefficient math overlaps the 49 in-flight staging ops.

#define H_IMG 14
#define W_IMG 14
#define L_NODES 196
#define B_SZ 32
#define NH 24
#define P_DIM 64
#define SLAB (L_NODES * P_DIM)   // 12544 floats = 49 KiB
#define NCHUNK (SLAB / 256)      // 49 wave-wide 1 KiB chunks

__global__ __launch_bounds__(64) void chimera_scan_kernel(
    const float* __restrict__ dt,       // [2, B, NH, 14, 14]
    const float* __restrict__ dt_bias,  // [NH]
    const float* __restrict__ x,        // [B, NH, 196, 64]
    const float* __restrict__ Dvec,     // [NH]
    float* __restrict__ out)            // [B, NH, 196, 64]
{
    const int bh   = blockIdx.x;        // b*NH + h
    const int h    = bh % NH;
    const int lane = threadIdx.x;       // channel p

    __shared__ float s_x[SLAB];         // 49 KiB x slab
    __shared__ float s_aL[L_NODES];
    __shared__ float s_aT[L_NODES];

    const float* dt0 = dt + (size_t)bh * L_NODES;
    const float* dt1 = dt0 + (size_t)(B_SZ * NH) * L_NODES;

    // --- 1) dt loads first: they occupy the OLDEST vmcnt slots, so the
    //        coefficient compute below waits only on them (vmcnt(49)),
    //        leaving all staging ops in flight. ---
    float d0v[4], d1v[4];
    #pragma unroll
    for (int k = 0; k < 4; ++k) {
        int i  = lane + 64 * k;
        int ic = (i < L_NODES) ? i : 0;   // clamp: harmless in-bounds read
        d0v[k] = dt0[ic];
        d1v[k] = dt1[ic];
    }

    // uniform scalars -> s_load (lgkmcnt, doesn't touch vmcnt)
    const float bias = dt_bias[h];
    const float Dh   = Dvec[h];

    // --- 2) issue HBM->LDS staging: 49 x global_load_lds_dwordx4.
    //        LDS dest = wave-uniform base + lane*16B (linear layout). ---
    const float* xb = x + (size_t)bh * SLAB;
    #pragma unroll
    for (int k = 0; k < NCHUNK; ++k) {
        __builtin_amdgcn_global_load_lds(
            (const __attribute__((address_space(1))) void*)(xb + k * 256 + lane * 4),
            (__attribute__((address_space(3))) void*)(s_x + k * 256),
            16, 0, 0);
    }

    // --- 3) coefficients (overlaps staging): aL = 0.95*sigmoid(-(dt0+b))*rs ---
    #pragma unroll
    for (int k = 0; k < 4; ++k) {
        int i = lane + 64 * k;
        if (i < L_NODES) {
            int r = i / W_IMG;
            int c = i - r * W_IMG;
            float rs   = (r > 0 && c > 0) ? 0.70710678118654752f : 1.0f;
            float coef = 0.95f * rs;
            // exp(-softplus(v)) == 1/(1+exp(v))
            s_aL[i] = (c > 0) ? coef / (1.0f + expf(d0v[k] + bias)) : 0.0f;
            s_aT[i] = (r > 0) ? coef / (1.0f + expf(d1v[k] + bias)) : 0.0f;
        }
    }

    // --- 4) drain staging, make LDS visible ---
    asm volatile("s_waitcnt vmcnt(0)" ::: "memory");
    __syncthreads();

    // --- 5) raster scan; y stored straight to global (no loads pending ->
    //        stores never trigger vmcnt waits) ---
    float* yb = out + (size_t)bh * SLAB + lane;
    float zrow[W_IMG];
    #pragma unroll
    for (int c = 0; c < W_IMG; ++c) zrow[c] = 0.0f;

    #pragma unroll
    for (int r = 0; r < H_IMG; ++r) {
        float zl = 0.0f;
        #pragma unroll
        for (int c = 0; c < W_IMG; ++c) {
            const int i  = r * W_IMG + c;
            float xi = s_x[i * P_DIM + lane];   // 2-way bank access: free
            float z  = fmaf(s_aL[i], zl, fmaf(s_aT[i], zrow[c], xi));
            zrow[c] = z;
            zl = z;
            yb[i * P_DIM] = fmaf(Dh, xi, z);
        }
    }
}

extern "C" void kernel_launch(void* const* d_in, const int* in_sizes, int n_in,
                              void* d_out, int out_size, void* d_ws, size_t ws_size,
                              hipStream_t stream) {
    const float* dt      = (const float*)d_in[0];
    const float* dt_bias = (const float*)d_in[1];
    const float* x       = (const float*)d_in[2];
    const float* Dvec    = (const float*)d_in[3];
    float* out = (float*)d_out;

    dim3 grid(B_SZ * NH);
    dim3 block(64);
    chimera_scan_kernel<<<grid, block, 0, stream>>>(dt, dt_bias, x, Dvec, out);
}